// Round 13
// baseline (174.459 us; speedup 1.0000x reference)
//
#include <hip/hip_runtime.h>

// ---------- types ----------
typedef __bf16 bf16x8 __attribute__((ext_vector_type(8)));
typedef float f32x4 __attribute__((ext_vector_type(4)));
typedef unsigned short u16x8 __attribute__((ext_vector_type(8)));

__device__ inline unsigned short f2bf(float f) {
  union { float f; unsigned u; } a; a.f = f;
  return (unsigned short)((a.u + 0x7fffu + ((a.u >> 16) & 1u)) >> 16); // RNE
}
__device__ inline float bf2f(unsigned short h) {
  union { unsigned u; float f; } a; a.u = ((unsigned)h) << 16;
  return a.f;
}

// ---------- fp32 -> bf16 conversion for Wq,Wk,Wv only (12 MB) ----------
__global__ __launch_bounds__(256) void cvtW(const float* __restrict__ Wq,
                                            const float* __restrict__ Wk,
                                            const float* __restrict__ Wv,
                                            unsigned short* __restrict__ Wb) {
  int i = blockIdx.x * 256 + threadIdx.x;   // 786432 float4 groups
  int idx = i >> 18;                        // 262144 float4 per W
  int off = i & 262143;
  const float* s = (idx == 0) ? Wq : ((idx == 1) ? Wk : Wv);
  float4 v = ((const float4*)s)[off];
  ushort4 o;
  o.x = f2bf(v.x); o.y = f2bf(v.y); o.z = f2bf(v.z); o.w = f2bf(v.w);
  ((ushort4*)(Wb + idx * 1048576))[off] = o;
}

#define G2L(gp, lp) __builtin_amdgcn_global_load_lds( \
    (const __attribute__((address_space(1))) void*)(gp), \
    (__attribute__((address_space(3))) void*)(lp), 16, 0, 0)

#define MFMA_(d, a, b) d = __builtin_amdgcn_mfma_f32_16x16x32_bf16(a, b, d, 0, 0, 0)
#define SB0() __builtin_amdgcn_sched_barrier(0)
#define LGKM(n) do { asm volatile("s_waitcnt lgkmcnt(" #n ")" ::: "memory"); SB0(); } while (0)
#define VMC(n) do { asm volatile("s_waitcnt vmcnt(" #n ")" ::: "memory"); SB0(); } while (0)

// =====================================================================
// gemmP v3 (ACVT at 2 WG/CU): fused projection GEMM, A fp32 from d_in,
// converted to bf16 in-register during staging (no cvt6 X round-trip).
// BM=BN=128, BK=64, 256 thr = 4 waves (2x2), wave tile 64x64.
// LDS 64KB = 2 bufs x (A 16KB + B 16KB) -> 2 WGs/CU (hides the relay;
// r7's 1-WG/CU ACVT serialized and lost).
// A relay: inst c loads rows [c*16,c*16+16) x 256B coalesced (lanes
// 0-15 contiguous) -> cvt -> 8x ds_write_b64 into the r4-verified
// 0-conflict layout: row r (128B), slot s holds k-group s^(r&7);
// reads use the r4 ck0/ck1 bytes unchanged. No spill: acc 64 + areg 32
// + frags 64 ~= 185 VGPR, no min-wave bound (r5 spilled at cap 128).
// Counted choreography: VMC(4) [ldA retired] -> wrA -> VMC(0) [B G2L]
// -> LGKM(0) [writes drained] -> barrier.
// =====================================================================
struct PJ {
  const float* A0; const float* A1; const float* A2;
  const unsigned short* B;                  // Wb (3 matrices)
  unsigned short* outQ; unsigned short* outK; unsigned short* outV;
  const float* biasQ; const float* biasK; const float* biasV;
};

__global__ __launch_bounds__(256) void gemmP(PJ p) {
  extern __shared__ char smem[];            // 65536: A 2x16384 | B 2x16384
  char* smA = smem;
  char* smB = smem + 32768;
  const int tid = threadIdx.x, lane = tid & 63, wid = tid >> 6;
  const int wm = wid >> 1, wn = wid & 1;

  // XCD swizzle, grid (8,64,3) = 1536 WGs (1536%8==0)
  int orig = blockIdx.x + 8 * (blockIdx.y + 64 * blockIdx.z);
  int wg = (orig & 7) * 192 + (orig >> 3);
  int bx = wg & 7; int t2 = wg >> 3; int by = t2 & 63; int z = t2 >> 6;
  const int m0 = by << 7, n0 = bx << 7;

  const float* Az = (z == 0) ? p.A0 : ((z == 1) ? p.A1 : p.A2);

  // A fp32 source: inst c reads row c*16 + (tid>>4), bytes (tid&15)*16
  const char* srcA0 = (const char*)Az + ((long long)m0 + (tid >> 4)) * 4096
                    + ((tid & 15) << 4);
  // A ds_write: inst c writes row rc = c*16 + (tid>>4),
  // slot g = (tid&15)>>1, half = tid&1 -> byte rc*128 + ((g^(rc&7))<<4) + half*8
  // B staging (r4-exact property): trow = tid>>3, slot const across chunks
  const int trow = tid >> 3;
  const int cs = (((tid & 7) ^ (trow & 7)) << 4);
  const char* srcB = (const char*)(p.B + (long long)z * 1048576
                                   + (long long)(n0 + trow) * 1024) + cs;

  // ds_read offsets (r4-exact bytes)
  const int aRowB = (((wm << 6) + (lane & 15)) << 7);
  const int bRowB = (((wn << 6) + (lane & 15)) << 7);
  const int csw = (lane & 7) << 4;
  const int ck0 = (((lane >> 4) << 4)) ^ csw;
  const int ck1 = ((((lane >> 4) << 4)) | 64) ^ csw;

  f32x4 acc[4][4];
#pragma unroll
  for (int i = 0; i < 4; ++i)
#pragma unroll
    for (int j = 0; j < 4; ++j) acc[i][j] = (f32x4){0.f, 0.f, 0.f, 0.f};

  float4 areg[8];
  bf16x8 aLo[2][2], aHi[2][2], bLo[2][2], bHi[2][2];

  auto ldA = [&](int t) {                   // 8 coalesced global_load_dwordx4
    const char* s = srcA0 + (long long)t * 256;
#pragma unroll
    for (int c = 0; c < 8; ++c)
      areg[c] = *(const float4*)(s + (long long)c * 65536); // 16 rows stride
  };
  auto wrA = [&](int t) {                   // cvt + 8x ds_write_b64
    char* dA = smA + ((t & 1) << 14);
    const int g = (tid & 15) >> 1;
    const int hb = (tid & 1) << 3;
#pragma unroll
    for (int c = 0; c < 8; ++c) {
      const int rc = (c << 4) + (tid >> 4);
      float4 v = areg[c];
      ushort4 o;
      o.x = f2bf(v.x); o.y = f2bf(v.y); o.z = f2bf(v.z); o.w = f2bf(v.w);
      *(ushort4*)(dA + (rc << 7) + ((g ^ (rc & 7)) << 4) + hb) = o;
    }
  };
  auto stageB = [&](int t) {                // 4 G2L chunks of 32 rows
    char* dB = smB + ((t & 1) << 14) + (tid << 4);
    const char* sB = srcB + (long long)t * 128;
#pragma unroll
    for (int c = 0; c < 4; ++c)
      G2L(sB + (long long)c * 65536, dB + (c << 12));
  };
  auto readAh = [&](int b, int half, bf16x8 (&dst)[2][2]) { // 4 ds_read_b128
    const char* ra = smA + (b << 14) + aRowB + (half << 12);
#pragma unroll
    for (int mi = 0; mi < 2; ++mi) {
      dst[mi][0] = *(const bf16x8*)(ra + (mi << 11) + ck0);
      dst[mi][1] = *(const bf16x8*)(ra + (mi << 11) + ck1);
    }
  };
  auto readBh = [&](int b, int half, bf16x8 (&dst)[2][2]) { // 4 ds_read_b128
    const char* rb = smB + (b << 14) + bRowB + (half << 12);
#pragma unroll
    for (int ni = 0; ni < 2; ++ni) {
      dst[ni][0] = *(const bf16x8*)(rb + (ni << 11) + ck0);
      dst[ni][1] = *(const bf16x8*)(rb + (ni << 11) + ck1);
    }
  };
  auto quad = [&](int qa, int qb, bf16x8 (&A)[2][2], bf16x8 (&B)[2][2]) {
    __builtin_amdgcn_s_setprio(1);
#pragma unroll
    for (int mi = 0; mi < 2; ++mi)
#pragma unroll
      for (int ni = 0; ni < 2; ++ni) {
        MFMA_(acc[qa * 2 + mi][qb * 2 + ni], A[mi][0], B[ni][0]);
        MFMA_(acc[qa * 2 + mi][qb * 2 + ni], A[mi][1], B[ni][1]);
      }
    __builtin_amdgcn_s_setprio(0);
  };

  // ---- prologue ----
  ldA(0); stageB(0);          // 8 + 4 vmem
  VMC(4);                     // ldA(0) retired (B G2L may fly)
  wrA(0);
  VMC(0);                     // B(0) in LDS
  LGKM(0);                    // writes drained
  __builtin_amdgcn_s_barrier();
  readAh(0, 0, aLo); readBh(0, 0, bLo);
  SB0();

  const int NT = 16;
  for (int t = 0; t < NT; ++t) {
    const bool pf = (t + 1) < NT;
    if (pf) { ldA(t + 1); stageB(t + 1); }   // 12 vmem, covered by body
    readAh(t & 1, 1, aHi);                   // lgkm out: 8 + 4
    SB0();
    LGKM(4);                                 // aLo,bLo ready
    quad(0, 0, aLo, bLo);
    readBh(t & 1, 1, bHi);                   // +4
    SB0();
    LGKM(4);                                 // aHi ready
    quad(1, 0, aHi, bLo);
    LGKM(0);                                 // bHi ready
    quad(0, 1, aLo, bHi);
    quad(1, 1, aHi, bHi);
    if (pf) {
      VMC(4);                                // ldA(t+1) retired
      wrA(t + 1);                            // writes OTHER buf (no WAR)
      VMC(0);                                // stageB(t+1) landed
    } else {
      VMC(0);
    }
    LGKM(0);                                 // ds_writes drained
    __builtin_amdgcn_s_barrier();
    if (pf) { readAh((t + 1) & 1, 0, aLo); readBh((t + 1) & 1, 0, bLo); }
    SB0();
  }

  // ---- epilogue: bias add; z<2 row-major; z==2 transposed vT[b][d][s] ----
  const int c0 = lane & 15, r0 = (lane >> 4) << 2;
  if (z < 2) {
    unsigned short* O = (z == 0) ? p.outQ : p.outK;
    const float* bias = (z == 0) ? p.biasQ : p.biasK;
#pragma unroll
    for (int mi = 0; mi < 4; ++mi) {
      const int grow = m0 + (wm << 6) + (mi << 4) + r0;
#pragma unroll
      for (int ni = 0; ni < 4; ++ni) {
        const int gcol = n0 + (wn << 6) + (ni << 4) + c0;
        const float bb = bias[gcol];
#pragma unroll
        for (int rr = 0; rr < 4; ++rr)
          O[(long long)(grow + rr) * 1024 + gcol] = f2bf(acc[mi][ni][rr] + bb);
      }
    }
  } else {
#pragma unroll
    for (int mi = 0; mi < 4; ++mi) {
      const int grow = m0 + (wm << 6) + (mi << 4) + r0;
      const int bb = grow >> 11, s = grow & 2047;
#pragma unroll
      for (int ni = 0; ni < 4; ++ni) {
        const int d = n0 + (wn << 6) + (ni << 4) + c0;
        const float ba = p.biasV[d];
        ushort4 pk;
        pk.x = f2bf(acc[mi][ni][0] + ba);
        pk.y = f2bf(acc[mi][ni][1] + ba);
        pk.z = f2bf(acc[mi][ni][2] + ba);
        pk.w = f2bf(acc[mi][ni][3] + ba);
        *(ushort4*)(p.outV + ((long long)bb << 21) + (long long)d * 2048 + s) = pk;
      }
    }
  }
}

// =====================================================================
// gemm2: r4-exact bf16 GEMM (BK=64, best measured for QK/PV).
// =====================================================================
#define EPI_SCALE 1
#define EPI_OUT 2

struct GP {
  const unsigned short* A;
  const unsigned short* B;
  unsigned short* C;            // bf16 (EPI_SCALE) or float* (EPI_OUT)
  long long batchA, batchB, batchC;
  int lda, ldb, ldc, K;
  float scale;
};

template<int BM, int BN, int WMW, int WNW, int EPI>
__global__ __launch_bounds__(512, 2) void gemm2(GP p) {
  constexpr int NWN = BN / WNW;
  constexpr int AMF = WMW / 16, BNF = WNW / 16;
  constexpr int AH = AMF / 2, BH = BNF / 2;
  constexpr int AF_N = AH * 2;
  constexpr int NBA = BM / 64, NBB = BN / 64;
  static_assert((BM / WMW) * NWN == 8, "8 waves");
  static_assert(BNF == 4, "lgkm immediates assume BNF==4");

  extern __shared__ char smem[];
  char* smA = smem;
  char* smB = smem + 2 * BM * 128;

  const int tid = threadIdx.x;
  const int lane = tid & 63;
  const int wid = tid >> 6;
  const int wm = wid / NWN, wn = wid % NWN;

  const int gx = gridDim.x, gy = gridDim.y;
  const int nwg = gx * gy * (int)gridDim.z;
  int orig = blockIdx.x + gx * (blockIdx.y + gy * blockIdx.z);
  int qq = nwg >> 3, rr_ = nwg & 7;
  int xcd = orig & 7, sl = orig >> 3;
  int wg = (xcd < rr_ ? xcd * (qq + 1) : rr_ * (qq + 1) + (xcd - rr_) * qq) + sl;
  int bx = wg % gx;
  int t2 = wg / gx;
  int by = t2 % gy;
  int z  = t2 / gy;

  const int m0 = by * BM, n0 = bx * BN;

  const long long lda2 = (long long)p.lda * 2;
  const long long ldb2 = (long long)p.ldb * 2;
  const char* Abase = (const char*)(p.A + (long long)z * p.batchA) + (long long)m0 * lda2;
  const char* Bbase = (const char*)(p.B + (long long)z * p.batchB) + (long long)n0 * ldb2;

  const int trow = tid >> 3;
  const int cs = (((tid & 7) ^ (trow & 7)) << 4);
  const char* srcA = Abase + (long long)trow * lda2 + cs;
  const char* srcB = Bbase + (long long)trow * ldb2 + cs;

  const int NT = p.K >> 6;

  const int aRowB = ((wm * WMW + (lane & 15)) << 7);
  const int bRowB = ((wn * WNW + (lane & 15)) << 7);
  const int csw = (lane & 7) << 4;
  const int ck0 = (((lane >> 4) << 4)) ^ csw;
  const int ck1 = ((((lane >> 4) << 4)) | 64) ^ csw;

  f32x4 acc[AMF][BNF];
#pragma unroll
  for (int i = 0; i < AMF; ++i)
#pragma unroll
    for (int j = 0; j < BNF; ++j) acc[i][j] = (f32x4){0.f, 0.f, 0.f, 0.f};

  bf16x8 aLo[AH][2], aHi[AH][2], bLo[BH][2], bHi[BH][2];

  auto stage = [&](int t) {
    char* dA = smA + (t & 1) * (BM * 128) + (tid << 4);
    char* dB = smB + (t & 1) * (BN * 128) + (tid << 4);
    const char* sA = srcA + (long long)t * 128;
    const char* sB = srcB + (long long)t * 128;
#pragma unroll
    for (int c = 0; c < NBA; ++c) G2L(sA + (long long)c * (lda2 << 6), dA + c * 8192);
#pragma unroll
    for (int c = 0; c < NBB; ++c) G2L(sB + (long long)c * (ldb2 << 6), dB + c * 8192);
  };
  auto readAh = [&](int t, int half, bf16x8 (&dst)[AH][2]) {
    const char* ra = smA + (t & 1) * (BM * 128) + aRowB + half * (AH * 2048);
#pragma unroll
    for (int mi = 0; mi < AH; ++mi) {
      dst[mi][0] = *(const bf16x8*)(ra + mi * 2048 + ck0);
      dst[mi][1] = *(const bf16x8*)(ra + mi * 2048 + ck1);
    }
  };
  auto readBh = [&](int t, int half, bf16x8 (&dst)[BH][2]) {
    const char* rb = smB + (t & 1) * (BN * 128) + bRowB + half * (BH * 2048);
#pragma unroll
    for (int ni = 0; ni < BH; ++ni) {
      dst[ni][0] = *(const bf16x8*)(rb + ni * 2048 + ck0);
      dst[ni][1] = *(const bf16x8*)(rb + ni * 2048 + ck1);
    }
  };
  auto quad = [&](int qa, int qb, bf16x8 (&A)[AH][2], bf16x8 (&B)[BH][2]) {
    __builtin_amdgcn_s_setprio(1);
#pragma unroll
    for (int mi = 0; mi < AH; ++mi)
#pragma unroll
      for (int ni = 0; ni < BH; ++ni) {
        MFMA_(acc[qa * AH + mi][qb * BH + ni], A[mi][0], B[ni][0]);
        MFMA_(acc[qa * AH + mi][qb * BH + ni], A[mi][1], B[ni][1]);
      }
    __builtin_amdgcn_s_setprio(0);
  };

  stage(0); stage(1);
  if constexpr (NBA + NBB == 8) VMC(8); else VMC(6);
  __builtin_amdgcn_s_barrier();
  readAh(0, 0, aLo); readBh(0, 0, bLo);
  SB0();

  for (int t = 0; t < NT; ++t) {
    readAh(t, 1, aHi);
    SB0();
    if constexpr (AF_N == 8) LGKM(8); else LGKM(4);
    quad(0, 0, aLo, bLo);
    readBh(t, 1, bHi);
    SB0();
    LGKM(4);
    quad(1, 0, aHi, bLo);
    LGKM(0);
    quad(0, 1, aLo, bHi);
    quad(1, 1, aHi, bHi);
    VMC(0);
    __builtin_amdgcn_s_barrier();
    if (t + 2 < NT) stage(t + 2);
    if (t + 1 < NT) { readAh(t + 1, 0, aLo); readBh(t + 1, 0, bLo); }
    SB0();
  }

  const int c0 = lane & 15;
  const int r0 = (lane >> 4) << 2;
  if constexpr (EPI == EPI_SCALE) {
    unsigned short* Cz = p.C + (long long)z * p.batchC;
#pragma unroll
    for (int mi = 0; mi < AMF; ++mi) {
      const int grow = m0 + wm * WMW + (mi << 4) + r0;
#pragma unroll
      for (int ni = 0; ni < BNF; ++ni) {
        const int gcol = n0 + wn * WNW + (ni << 4) + c0;
#pragma unroll
        for (int rr = 0; rr < 4; ++rr)
          Cz[(long long)(grow + rr) * p.ldc + gcol] = f2bf(acc[mi][ni][rr] * p.scale);
      }
    }
  } else {
    float* Cz = (float*)p.C + (long long)z * p.batchC;
#pragma unroll
    for (int mi = 0; mi < AMF; ++mi) {
      const int grow = m0 + wm * WMW + (mi << 4) + r0;
#pragma unroll
      for (int ni = 0; ni < BNF; ++ni) {
        const int gcol = n0 + wn * WNW + (ni << 4) + c0;
#pragma unroll
        for (int rr = 0; rr < 4; ++rr)
          Cz[(long long)(grow + rr) * p.ldc + gcol] = acc[mi][ni][rr] * p.scale;
      }
    }
  }
}

// ---------- row softmax over S[4][2048][2048] (bf16, in place) ----------
__global__ __launch_bounds__(256) void softmax_rows(unsigned short* __restrict__ S) {
  const size_t row = blockIdx.x;
  unsigned short* pp = S + row * 2048;
  const int t = threadIdx.x, lane = t & 63, wave = t >> 6;
  u16x8 h = ((const u16x8*)pp)[t];
  float x[8];
#pragma unroll
  for (int j = 0; j < 8; ++j) x[j] = bf2f(h[j]);
  float m = x[0];
#pragma unroll
  for (int j = 1; j < 8; ++j) m = fmaxf(m, x[j]);
#pragma unroll
  for (int off = 32; off >= 1; off >>= 1) m = fmaxf(m, __shfl_xor(m, off, 64));
  __shared__ float rmax[4], rsum[4];
  if (lane == 0) rmax[wave] = m;
  __syncthreads();
  m = fmaxf(fmaxf(rmax[0], rmax[1]), fmaxf(rmax[2], rmax[3]));
  float e[8], sum = 0.f;
#pragma unroll
  for (int j = 0; j < 8; ++j) { e[j] = __expf(x[j] - m); sum += e[j]; }
#pragma unroll
  for (int off = 32; off >= 1; off >>= 1) sum += __shfl_xor(sum, off, 64);
  if (lane == 0) rsum[wave] = sum;
  __syncthreads();
  sum = rsum[0] + rsum[1] + rsum[2] + rsum[3];
  const float inv = 1.f / sum;
  u16x8 o;
#pragma unroll
  for (int j = 0; j < 8; ++j) o[j] = f2bf(e[j] * inv);
  ((u16x8*)pp)[t] = o;
}

// ---------- launch ----------
extern "C" void kernel_launch(void* const* d_in, const int* in_sizes, int n_in,
                              void* d_out, int out_size, void* d_ws, size_t ws_size,
                              hipStream_t stream) {
  const float* q  = (const float*)d_in[0];
  const float* k  = (const float*)d_in[1];
  const float* v  = (const float*)d_in[2];
  const float* Wq = (const float*)d_in[3];
  const float* bq = (const float*)d_in[4];
  const float* Wk = (const float*)d_in[5];
  const float* bk = (const float*)d_in[6];
  const float* Wv = (const float*)d_in[7];
  const float* bv = (const float*)d_in[8];

  // workspace (u16 elems): S 32MB, Wb 6MB, qb 16MB, kb 16MB, vT 16MB = 86MB
  unsigned short* S  = (unsigned short*)d_ws;
  unsigned short* Wb = S + 16777216;
  unsigned short* qb = Wb + 3145728;
  unsigned short* kb = qb + 8388608;
  unsigned short* vT = kb + 8388608;

  (void)hipFuncSetAttribute((const void*)gemmP,
      hipFuncAttributeMaxDynamicSharedMemorySize, 65536);
  (void)hipFuncSetAttribute((const void*)gemm2<256,256,128,64,EPI_SCALE>,
      hipFuncAttributeMaxDynamicSharedMemorySize, 131072);
  (void)hipFuncSetAttribute((const void*)gemm2<256,128,64,64,EPI_OUT>,
      hipFuncAttributeMaxDynamicSharedMemorySize, 98304);

  cvtW<<<3072, 256, 0, stream>>>(Wq, Wk, Wv, Wb);

  // fused q/k/v projections, A fp32 converted in-register during staging:
  // per z, M=8192, N=1024, K=1024; 1536 WGs (128^2, 256 thr), 2 WGs/CU
  PJ pj{};
  pj.A0 = q; pj.A1 = k; pj.A2 = v;
  pj.B = Wb;
  pj.outQ = qb; pj.outK = kb; pj.outV = vT;
  pj.biasQ = bq; pj.biasK = bk; pj.biasV = bv;
  gemmP<<<dim3(8, 64, 3), 256, 65536, stream>>>(pj);

  // scores = q @ k^T * scale : per batch M=2048, N=2048, K=1024 (256 WGs)
  GP gs{};
  gs.A = qb; gs.batchA = 2097152; gs.lda = 1024;
  gs.B = kb; gs.batchB = 2097152; gs.ldb = 1024;
  gs.C = S;  gs.batchC = 4194304; gs.ldc = 2048;
  gs.K = 1024; gs.scale = 0.03125f;
  gemm2<256,256,128,64,EPI_SCALE><<<dim3(8, 8, 4), 512, 131072, stream>>>(gs);

  softmax_rows<<<8192, 256, 0, stream>>>(S);

  // out = P @ V : M=2048, N=1024, K=2048 per batch (256 WGs)
  GP gv{};
  gv.A = S;  gv.batchA = 4194304; gv.lda = 2048;
  gv.B = vT; gv.batchB = 2097152; gv.ldb = 2048;
  gv.C = (unsigned short*)d_out; gv.batchC = 2097152; gv.ldc = 1024;
  gv.K = 2048; gv.scale = 1.f;
  gemm2<256,128,64,64,EPI_OUT><<<dim3(8, 8, 4), 512, 98304, stream>>>(gv);
}

// Round 14
// 166.935 us; speedup vs baseline: 1.0451x; 1.0451x over previous
//
#include <hip/hip_runtime.h>

// ---------- types ----------
typedef __bf16 bf16x8 __attribute__((ext_vector_type(8)));
typedef float f32x4 __attribute__((ext_vector_type(4)));
typedef unsigned short u16x8 __attribute__((ext_vector_type(8)));

__device__ inline unsigned short f2bf(float f) {
  union { float f; unsigned u; } a; a.f = f;
  return (unsigned short)((a.u + 0x7fffu + ((a.u >> 16) & 1u)) >> 16); // RNE
}
__device__ inline float bf2f(unsigned short h) {
  union { unsigned u; float f; } a; a.u = ((unsigned)h) << 16;
  return a.f;
}

// ---------- fp32 -> bf16 conversion for Wq,Wk,Wv only (12 MB) ----------
__global__ __launch_bounds__(256) void cvtW(const float* __restrict__ Wq,
                                            const float* __restrict__ Wk,
                                            const float* __restrict__ Wv,
                                            unsigned short* __restrict__ Wb) {
  int i = blockIdx.x * 256 + threadIdx.x;   // 786432 float4 groups
  int idx = i >> 18;                        // 262144 float4 per W
  int off = i & 262143;
  const float* s = (idx == 0) ? Wq : ((idx == 1) ? Wk : Wv);
  float4 v = ((const float4*)s)[off];
  ushort4 o;
  o.x = f2bf(v.x); o.y = f2bf(v.y); o.z = f2bf(v.z); o.w = f2bf(v.w);
  ((ushort4*)(Wb + idx * 1048576))[off] = o;
}

#define G2L(gp, lp) __builtin_amdgcn_global_load_lds( \
    (const __attribute__((address_space(1))) void*)(gp), \
    (__attribute__((address_space(3))) void*)(lp), 16, 0, 0)

#define MFMA_(d, a, b) d = __builtin_amdgcn_mfma_f32_16x16x32_bf16(a, b, d, 0, 0, 0)
#define SB0() __builtin_amdgcn_sched_barrier(0)
#define LGKM(n) do { asm volatile("s_waitcnt lgkmcnt(" #n ")" ::: "memory"); SB0(); } while (0)
#define VMC(n) do { asm volatile("s_waitcnt vmcnt(" #n ")" ::: "memory"); SB0(); } while (0)

// =====================================================================
// gemmP v4: ACVT with deep prefetch. A fp32 from d_in, cvt in-register
// (PLAIN __bf16 casts -> v_cvt_pk_bf16_f32; r13's manual-RNE f2bf was
// 31.7% VALUBusy). BM=BN=128, BK=64, 256 thr = 4 waves (2x2).
// LDS 80KB = A 2x16KB + B 3x16KB -> 2 WGs/CU.
// Deep pipeline: ldA(t+2)+stageB(t+2) issued at TOP of tile t (dual
// named areg sets, pair-unrolled; B 3-buf rotation); bottom-of-tile
// wait is counted VMC(12) = retire exactly ldA(t+1)+stageB(t+1),
// keep t+2 in flight (T4 never-drain). ~2 tile bodies of HBM cover
// (r13 had 1 body -> ~500cyc exposed stall -> MfmaUtil 16.8%).
// A LDS layout r4-verified 0-conflict: row r = 128B line, slot s holds
// k-group s^(r&7); reads ck0/ck1 bytes r4-exact.
// =====================================================================
struct PJ {
  const float* A0; const float* A1; const float* A2;
  const unsigned short* B;                  // Wb (3 matrices)
  unsigned short* outQ; unsigned short* outK; unsigned short* outV;
  const float* biasQ; const float* biasK; const float* biasV;
};

__global__ __launch_bounds__(256) void gemmP(PJ p) {
  extern __shared__ char smem[];            // 81920: A 2x16384 | B 3x16384
  char* smA = smem;
  char* smB = smem + 32768;
  const int tid = threadIdx.x, lane = tid & 63, wid = tid >> 6;
  const int wm = wid >> 1, wn = wid & 1;

  // XCD swizzle, grid (8,64,3) = 1536 WGs (1536%8==0)
  int orig = blockIdx.x + 8 * (blockIdx.y + 64 * blockIdx.z);
  int wg = (orig & 7) * 192 + (orig >> 3);
  int bx = wg & 7; int t2 = wg >> 3; int by = t2 & 63; int z = t2 >> 6;
  const int m0 = by << 7, n0 = bx << 7;

  const float* Az = (z == 0) ? p.A0 : ((z == 1) ? p.A1 : p.A2);

  // A fp32 source: inst c reads row c*16 + (tid>>4), bytes (tid&15)*16
  const char* srcA0 = (const char*)Az + ((long long)m0 + (tid >> 4)) * 4096
                    + ((tid & 15) << 4);
  // B staging (r4-exact): trow = tid>>3, pre-inverse-swizzled col
  const int trow = tid >> 3;
  const int cs = (((tid & 7) ^ (trow & 7)) << 4);
  const char* srcB = (const char*)(p.B + (long long)z * 1048576
                                   + (long long)(n0 + trow) * 1024) + cs;

  // ds_read offsets (r4-exact bytes)
  const int aRowB = (((wm << 6) + (lane & 15)) << 7);
  const int bRowB = (((wn << 6) + (lane & 15)) << 7);
  const int csw = (lane & 7) << 4;
  const int ck0 = (((lane >> 4) << 4)) ^ csw;
  const int ck1 = ((((lane >> 4) << 4)) | 64) ^ csw;

  f32x4 acc[4][4];
#pragma unroll
  for (int i = 0; i < 4; ++i)
#pragma unroll
    for (int j = 0; j < 4; ++j) acc[i][j] = (f32x4){0.f, 0.f, 0.f, 0.f};

  float4 aregA[8], aregB[8];
  bf16x8 aLo[2][2], aHi[2][2], bLo[2][2], bHi[2][2];

  auto ldA = [&](int t, float4 (&ar)[8]) {  // 8 coalesced global_load_dwordx4
    const char* s = srcA0 + (long long)t * 256;
#pragma unroll
    for (int c = 0; c < 8; ++c)
      ar[c] = *(const float4*)(s + (long long)c * 65536); // 16-row stride
  };
  auto wrA = [&](int t, float4 (&ar)[8]) {  // plain-cast cvt + 8x ds_write_b64
    char* dA = smA + ((t & 1) << 14);
    const int g = (tid & 15) >> 1;
    const int hb = (tid & 1) << 3;
#pragma unroll
    for (int c = 0; c < 8; ++c) {
      const int rc = (c << 4) + (tid >> 4);
      float4 v = ar[c];
      union { __bf16 b[4]; ushort4 u; } o;
      o.b[0] = (__bf16)v.x; o.b[1] = (__bf16)v.y;
      o.b[2] = (__bf16)v.z; o.b[3] = (__bf16)v.w;
      *(ushort4*)(dA + (rc << 7) + ((g ^ (rc & 7)) << 4) + hb) = o.u;
    }
  };
  auto stageB = [&](int t, int b) {         // 4 G2L chunks of 32 rows
    char* dB = smB + (b << 14) + (tid << 4);
    const char* sB = srcB + (long long)t * 128;
#pragma unroll
    for (int c = 0; c < 4; ++c)
      G2L(sB + (long long)c * 65536, dB + (c << 12));
  };
  auto readAh = [&](int b, int half, bf16x8 (&dst)[2][2]) { // 4 ds_read_b128
    const char* ra = smA + (b << 14) + aRowB + (half << 12);
#pragma unroll
    for (int mi = 0; mi < 2; ++mi) {
      dst[mi][0] = *(const bf16x8*)(ra + (mi << 11) + ck0);
      dst[mi][1] = *(const bf16x8*)(ra + (mi << 11) + ck1);
    }
  };
  auto readBh = [&](int b, int half, bf16x8 (&dst)[2][2]) { // 4 ds_read_b128
    const char* rb = smB + (b << 14) + bRowB + (half << 12);
#pragma unroll
    for (int ni = 0; ni < 2; ++ni) {
      dst[ni][0] = *(const bf16x8*)(rb + (ni << 11) + ck0);
      dst[ni][1] = *(const bf16x8*)(rb + (ni << 11) + ck1);
    }
  };
  auto quad = [&](int qa, int qb, bf16x8 (&A)[2][2], bf16x8 (&B)[2][2]) {
    __builtin_amdgcn_s_setprio(1);
#pragma unroll
    for (int mi = 0; mi < 2; ++mi)
#pragma unroll
      for (int ni = 0; ni < 2; ++ni) {
        MFMA_(acc[qa * 2 + mi][qb * 2 + ni], A[mi][0], B[ni][0]);
        MFMA_(acc[qa * 2 + mi][qb * 2 + ni], A[mi][1], B[ni][1]);
      }
    __builtin_amdgcn_s_setprio(0);
  };

  const int NT = 16;
  int b0 = 0, b1 = 1, b2 = 2;               // B buf of t, t+1, t+2

  // ---- prologue: tiles 0,1 in flight; land 0; pre-read 0 ----
  ldA(0, aregA); stageB(0, 0);              // 8 + 4
  ldA(1, aregB); stageB(1, 1);              // 8 + 4 (24 outstanding)
  VMC(12);                                  // ldA(0)+stageB(0) retired
  wrA(0, aregA);
  LGKM(0);                                  // ds_writes drained
  __builtin_amdgcn_s_barrier();
  readAh(0, 0, aLo); readBh(0, 0, bLo);
  SB0();

  auto body = [&](int t, float4 (&arW)[8], float4 (&arL)[8]) {
    const bool pf1 = (t + 1) < NT, pf2 = (t + 2) < NT;
    if (pf2) { ldA(t + 2, arL); stageB(t + 2, b2); }  // 12 vmem issued
    readAh(t & 1, 1, aHi);                   // lgkm: 8 (pre-read) + 4
    SB0();
    LGKM(4);                                 // aLo,bLo ready
    quad(0, 0, aLo, bLo);
    readBh(b0, 1, bHi);                      // +4
    SB0();
    LGKM(4);                                 // aHi ready
    quad(1, 0, aHi, bLo);
    LGKM(0);                                 // bHi ready
    quad(0, 1, aLo, bHi);
    quad(1, 1, aHi, bHi);
    if (pf2) { VMC(12); }                    // ldA(t+1)+stageB(t+1) retired;
    else     { VMC(0);  }                    //   t+2 stays in flight
    if (pf1) wrA(t + 1, arW);                // other A buf (no WAR)
    LGKM(0);                                 // ds_writes drained
    __builtin_amdgcn_s_barrier();
    if (pf1) { readAh((t + 1) & 1, 0, aLo); readBh(b1, 0, bLo); }
    SB0();
    int tmp = b0; b0 = b1; b1 = b2; b2 = tmp;
  };
  for (int t = 0; t < NT; t += 2) { body(t, aregB, aregA); body(t + 1, aregA, aregB); }

  // ---- epilogue: bias add; z<2 row-major; z==2 transposed vT[b][d][s] ----
  const int c0 = lane & 15, r0 = (lane >> 4) << 2;
  if (z < 2) {
    unsigned short* O = (z == 0) ? p.outQ : p.outK;
    const float* bias = (z == 0) ? p.biasQ : p.biasK;
#pragma unroll
    for (int mi = 0; mi < 4; ++mi) {
      const int grow = m0 + (wm << 6) + (mi << 4) + r0;
#pragma unroll
      for (int ni = 0; ni < 4; ++ni) {
        const int gcol = n0 + (wn << 6) + (ni << 4) + c0;
        const float bb = bias[gcol];
#pragma unroll
        for (int rr = 0; rr < 4; ++rr)
          O[(long long)(grow + rr) * 1024 + gcol] = f2bf(acc[mi][ni][rr] + bb);
      }
    }
  } else {
#pragma unroll
    for (int mi = 0; mi < 4; ++mi) {
      const int grow = m0 + (wm << 6) + (mi << 4) + r0;
      const int bb = grow >> 11, s = grow & 2047;
#pragma unroll
      for (int ni = 0; ni < 4; ++ni) {
        const int d = n0 + (wn << 6) + (ni << 4) + c0;
        const float ba = p.biasV[d];
        ushort4 pk;
        pk.x = f2bf(acc[mi][ni][0] + ba);
        pk.y = f2bf(acc[mi][ni][1] + ba);
        pk.z = f2bf(acc[mi][ni][2] + ba);
        pk.w = f2bf(acc[mi][ni][3] + ba);
        *(ushort4*)(p.outV + ((long long)bb << 21) + (long long)d * 2048 + s) = pk;
      }
    }
  }
}

// =====================================================================
// gemm2: r4-exact bf16 GEMM (BK=64, best measured for QK/PV).
// =====================================================================
#define EPI_SCALE 1
#define EPI_OUT 2

struct GP {
  const unsigned short* A;
  const unsigned short* B;
  unsigned short* C;            // bf16 (EPI_SCALE) or float* (EPI_OUT)
  long long batchA, batchB, batchC;
  int lda, ldb, ldc, K;
  float scale;
};

template<int BM, int BN, int WMW, int WNW, int EPI>
__global__ __launch_bounds__(512, 2) void gemm2(GP p) {
  constexpr int NWN = BN / WNW;
  constexpr int AMF = WMW / 16, BNF = WNW / 16;
  constexpr int AH = AMF / 2, BH = BNF / 2;
  constexpr int AF_N = AH * 2;
  constexpr int NBA = BM / 64, NBB = BN / 64;
  static_assert((BM / WMW) * NWN == 8, "8 waves");
  static_assert(BNF == 4, "lgkm immediates assume BNF==4");

  extern __shared__ char smem[];
  char* smA = smem;
  char* smB = smem + 2 * BM * 128;

  const int tid = threadIdx.x;
  const int lane = tid & 63;
  const int wid = tid >> 6;
  const int wm = wid / NWN, wn = wid % NWN;

  const int gx = gridDim.x, gy = gridDim.y;
  const int nwg = gx * gy * (int)gridDim.z;
  int orig = blockIdx.x + gx * (blockIdx.y + gy * blockIdx.z);
  int qq = nwg >> 3, rr_ = nwg & 7;
  int xcd = orig & 7, sl = orig >> 3;
  int wg = (xcd < rr_ ? xcd * (qq + 1) : rr_ * (qq + 1) + (xcd - rr_) * qq) + sl;
  int bx = wg % gx;
  int t2 = wg / gx;
  int by = t2 % gy;
  int z  = t2 / gy;

  const int m0 = by * BM, n0 = bx * BN;

  const long long lda2 = (long long)p.lda * 2;
  const long long ldb2 = (long long)p.ldb * 2;
  const char* Abase = (const char*)(p.A + (long long)z * p.batchA) + (long long)m0 * lda2;
  const char* Bbase = (const char*)(p.B + (long long)z * p.batchB) + (long long)n0 * ldb2;

  const int trow = tid >> 3;
  const int cs = (((tid & 7) ^ (trow & 7)) << 4);
  const char* srcA = Abase + (long long)trow * lda2 + cs;
  const char* srcB = Bbase + (long long)trow * ldb2 + cs;

  const int NT = p.K >> 6;

  const int aRowB = ((wm * WMW + (lane & 15)) << 7);
  const int bRowB = ((wn * WNW + (lane & 15)) << 7);
  const int csw = (lane & 7) << 4;
  const int ck0 = (((lane >> 4) << 4)) ^ csw;
  const int ck1 = ((((lane >> 4) << 4)) | 64) ^ csw;

  f32x4 acc[AMF][BNF];
#pragma unroll
  for (int i = 0; i < AMF; ++i)
#pragma unroll
    for (int j = 0; j < BNF; ++j) acc[i][j] = (f32x4){0.f, 0.f, 0.f, 0.f};

  bf16x8 aLo[AH][2], aHi[AH][2], bLo[BH][2], bHi[BH][2];

  auto stage = [&](int t) {
    char* dA = smA + (t & 1) * (BM * 128) + (tid << 4);
    char* dB = smB + (t & 1) * (BN * 128) + (tid << 4);
    const char* sA = srcA + (long long)t * 128;
    const char* sB = srcB + (long long)t * 128;
#pragma unroll
    for (int c = 0; c < NBA; ++c) G2L(sA + (long long)c * (lda2 << 6), dA + c * 8192);
#pragma unroll
    for (int c = 0; c < NBB; ++c) G2L(sB + (long long)c * (ldb2 << 6), dB + c * 8192);
  };
  auto readAh = [&](int t, int half, bf16x8 (&dst)[AH][2]) {
    const char* ra = smA + (t & 1) * (BM * 128) + aRowB + half * (AH * 2048);
#pragma unroll
    for (int mi = 0; mi < AH; ++mi) {
      dst[mi][0] = *(const bf16x8*)(ra + mi * 2048 + ck0);
      dst[mi][1] = *(const bf16x8*)(ra + mi * 2048 + ck1);
    }
  };
  auto readBh = [&](int t, int half, bf16x8 (&dst)[BH][2]) {
    const char* rb = smB + (t & 1) * (BN * 128) + bRowB + half * (BH * 2048);
#pragma unroll
    for (int ni = 0; ni < BH; ++ni) {
      dst[ni][0] = *(const bf16x8*)(rb + ni * 2048 + ck0);
      dst[ni][1] = *(const bf16x8*)(rb + ni * 2048 + ck1);
    }
  };
  auto quad = [&](int qa, int qb, bf16x8 (&A)[AH][2], bf16x8 (&B)[BH][2]) {
    __builtin_amdgcn_s_setprio(1);
#pragma unroll
    for (int mi = 0; mi < AH; ++mi)
#pragma unroll
      for (int ni = 0; ni < BH; ++ni) {
        MFMA_(acc[qa * AH + mi][qb * BH + ni], A[mi][0], B[ni][0]);
        MFMA_(acc[qa * AH + mi][qb * BH + ni], A[mi][1], B[ni][1]);
      }
    __builtin_amdgcn_s_setprio(0);
  };

  stage(0); stage(1);
  if constexpr (NBA + NBB == 8) VMC(8); else VMC(6);
  __builtin_amdgcn_s_barrier();
  readAh(0, 0, aLo); readBh(0, 0, bLo);
  SB0();

  for (int t = 0; t < NT; ++t) {
    readAh(t, 1, aHi);
    SB0();
    if constexpr (AF_N == 8) LGKM(8); else LGKM(4);
    quad(0, 0, aLo, bLo);
    readBh(t, 1, bHi);
    SB0();
    LGKM(4);
    quad(1, 0, aHi, bLo);
    LGKM(0);
    quad(0, 1, aLo, bHi);
    quad(1, 1, aHi, bHi);
    VMC(0);
    __builtin_amdgcn_s_barrier();
    if (t + 2 < NT) stage(t + 2);
    if (t + 1 < NT) { readAh(t + 1, 0, aLo); readBh(t + 1, 0, bLo); }
    SB0();
  }

  const int c0 = lane & 15;
  const int r0 = (lane >> 4) << 2;
  if constexpr (EPI == EPI_SCALE) {
    unsigned short* Cz = p.C + (long long)z * p.batchC;
#pragma unroll
    for (int mi = 0; mi < AMF; ++mi) {
      const int grow = m0 + wm * WMW + (mi << 4) + r0;
#pragma unroll
      for (int ni = 0; ni < BNF; ++ni) {
        const int gcol = n0 + wn * WNW + (ni << 4) + c0;
#pragma unroll
        for (int rr = 0; rr < 4; ++rr)
          Cz[(long long)(grow + rr) * p.ldc + gcol] = f2bf(acc[mi][ni][rr] * p.scale);
      }
    }
  } else {
    float* Cz = (float*)p.C + (long long)z * p.batchC;
#pragma unroll
    for (int mi = 0; mi < AMF; ++mi) {
      const int grow = m0 + wm * WMW + (mi << 4) + r0;
#pragma unroll
      for (int ni = 0; ni < BNF; ++ni) {
        const int gcol = n0 + wn * WNW + (ni << 4) + c0;
#pragma unroll
        for (int rr = 0; rr < 4; ++rr)
          Cz[(long long)(grow + rr) * p.ldc + gcol] = acc[mi][ni][rr] * p.scale;
      }
    }
  }
}

// ---------- row softmax over S[4][2048][2048] (bf16, in place) ----------
__global__ __launch_bounds__(256) void softmax_rows(unsigned short* __restrict__ S) {
  const size_t row = blockIdx.x;
  unsigned short* pp = S + row * 2048;
  const int t = threadIdx.x, lane = t & 63, wave = t >> 6;
  u16x8 h = ((const u16x8*)pp)[t];
  float x[8];
#pragma unroll
  for (int j = 0; j < 8; ++j) x[j] = bf2f(h[j]);
  float m = x[0];
#pragma unroll
  for (int j = 1; j < 8; ++j) m = fmaxf(m, x[j]);
#pragma unroll
  for (int off = 32; off >= 1; off >>= 1) m = fmaxf(m, __shfl_xor(m, off, 64));
  __shared__ float rmax[4], rsum[4];
  if (lane == 0) rmax[wave] = m;
  __syncthreads();
  m = fmaxf(fmaxf(rmax[0], rmax[1]), fmaxf(rmax[2], rmax[3]));
  float e[8], sum = 0.f;
#pragma unroll
  for (int j = 0; j < 8; ++j) { e[j] = __expf(x[j] - m); sum += e[j]; }
#pragma unroll
  for (int off = 32; off >= 1; off >>= 1) sum += __shfl_xor(sum, off, 64);
  if (lane == 0) rsum[wave] = sum;
  __syncthreads();
  sum = rsum[0] + rsum[1] + rsum[2] + rsum[3];
  const float inv = 1.f / sum;
  u16x8 o;
#pragma unroll
  for (int j = 0; j < 8; ++j) o[j] = f2bf(e[j] * inv);
  ((u16x8*)pp)[t] = o;
}

// ---------- launch ----------
extern "C" void kernel_launch(void* const* d_in, const int* in_sizes, int n_in,
                              void* d_out, int out_size, void* d_ws, size_t ws_size,
                              hipStream_t stream) {
  const float* q  = (const float*)d_in[0];
  const float* k  = (const float*)d_in[1];
  const float* v  = (const float*)d_in[2];
  const float* Wq = (const float*)d_in[3];
  const float* bq = (const float*)d_in[4];
  const float* Wk = (const float*)d_in[5];
  const float* bk = (const float*)d_in[6];
  const float* Wv = (const float*)d_in[7];
  const float* bv = (const float*)d_in[8];

  // workspace (u16 elems): S 32MB, Wb 6MB, qb 16MB, kb 16MB, vT 16MB = 86MB
  unsigned short* S  = (unsigned short*)d_ws;
  unsigned short* Wb = S + 16777216;
  unsigned short* qb = Wb + 3145728;
  unsigned short* kb = qb + 8388608;
  unsigned short* vT = kb + 8388608;

  (void)hipFuncSetAttribute((const void*)gemmP,
      hipFuncAttributeMaxDynamicSharedMemorySize, 81920);
  (void)hipFuncSetAttribute((const void*)gemm2<256,256,128,64,EPI_SCALE>,
      hipFuncAttributeMaxDynamicSharedMemorySize, 131072);
  (void)hipFuncSetAttribute((const void*)gemm2<256,128,64,64,EPI_OUT>,
      hipFuncAttributeMaxDynamicSharedMemorySize, 98304);

  cvtW<<<3072, 256, 0, stream>>>(Wq, Wk, Wv, Wb);

  // fused q/k/v projections, A fp32 converted in-register during staging:
  // per z, M=8192, N=1024, K=1024; 1536 WGs (128^2, 256 thr), 2 WGs/CU
  PJ pj{};
  pj.A0 = q; pj.A1 = k; pj.A2 = v;
  pj.B = Wb;
  pj.outQ = qb; pj.outK = kb; pj.outV = vT;
  pj.biasQ = bq; pj.biasK = bk; pj.biasV = bv;
  gemmP<<<dim3(8, 64, 3), 256, 81920, stream>>>(pj);

  // scores = q @ k^T * scale : per batch M=2048, N=2048, K=1024 (256 WGs)
  GP gs{};
  gs.A = qb; gs.batchA = 2097152; gs.lda = 1024;
  gs.B = kb; gs.batchB = 2097152; gs.ldb = 1024;
  gs.C = S;  gs.batchC = 4194304; gs.ldc = 2048;
  gs.K = 1024; gs.scale = 0.03125f;
  gemm2<256,256,128,64,EPI_SCALE><<<dim3(8, 8, 4), 512, 131072, stream>>>(gs);

  softmax_rows<<<8192, 256, 0, stream>>>(S);

  // out = P @ V : M=2048, N=1024, K=2048 per batch (256 WGs)
  GP gv{};
  gv.A = S;  gv.batchA = 4194304; gv.lda = 2048;
  gv.B = vT; gv.batchB = 2097152; gv.ldb = 2048;
  gv.C = (unsigned short*)d_out; gv.batchC = 2097152; gv.ldc = 1024;
  gv.K = 2048; gv.scale = 1.f;
  gemm2<256,128,64,64,EPI_OUT><<<dim3(8, 8, 4), 512, 98304, stream>>>(gv);
}